// Round 1
// baseline (512.293 us; speedup 1.0000x reference)
//
#include <hip/hip_runtime.h>
#include <stdint.h>

#define D 128

typedef __attribute__((ext_vector_type(8))) short bf16x8;
typedef __attribute__((ext_vector_type(4))) float f32x4;
typedef __attribute__((ext_vector_type(2))) float f32x2;
typedef unsigned short u16;
typedef unsigned char u8;
typedef unsigned int u32;

static __device__ __forceinline__ float b2f(u16 u) {
  return __uint_as_float(((unsigned)u) << 16);
}
static __device__ __forceinline__ u16 f2b(float f) {
  unsigned u = __float_as_uint(f);
  return (u16)((u + 0x7fffu + ((u >> 16) & 1u)) >> 16);
}

// ------------------------------ fp8 e4m3 -----------------------------------
#if defined(__has_builtin)
#if __has_builtin(__builtin_amdgcn_cvt_pk_f32_fp8) && __has_builtin(__builtin_amdgcn_cvt_pk_fp8_f32)
#define HW_FP8 1
#endif
#endif

static __device__ __forceinline__ u8 enc_fp8(float f) {
#ifdef HW_FP8
  int p = __builtin_amdgcn_cvt_pk_fp8_f32(f, 0.f, 0, false);
  return (u8)(p & 0xff);
#else
  float a = fabsf(f);
  unsigned s = (__float_as_uint(f) >> 31) << 7;
  if (a < 7.8125e-3f) {
    int m = (int)(a * 512.f + 0.5f);
    if (m > 7) m = 7;
    return (u8)(s | m);
  }
  int e; float mant = frexpf(a, &e);
  int E = e + 6;
  int m = (int)((2.f * mant - 1.f) * 8.f + 0.5f);
  if (m == 8) { m = 0; E++; }
  if (E > 15 || (E == 15 && m > 6)) { E = 15; m = 6; }
  if (E < 1) return (u8)s;
  return (u8)(s | (E << 3) | m);
#endif
}

static __device__ __forceinline__ float dec1_fp8(u8 b) {
  int e = (b >> 3) & 15, m = b & 7;
  float mag = e ? ldexpf((float)(8 + m), e - 10) : ldexpf((float)m, -9);
  return (b & 128) ? -mag : mag;
}

static __device__ __forceinline__ void dec8_fp8(u32 lo, u32 hi, float* o) {
#ifdef HW_FP8
  f32x2 a = __builtin_amdgcn_cvt_pk_f32_fp8((int)lo, false);
  f32x2 b = __builtin_amdgcn_cvt_pk_f32_fp8((int)lo, true);
  f32x2 c = __builtin_amdgcn_cvt_pk_f32_fp8((int)hi, false);
  f32x2 d = __builtin_amdgcn_cvt_pk_f32_fp8((int)hi, true);
  o[0] = a.x; o[1] = a.y; o[2] = b.x; o[3] = b.y;
  o[4] = c.x; o[5] = c.y; o[6] = d.x; o[7] = d.y;
#else
  u32 w[2] = {lo, hi};
  u8* p = (u8*)w;
#pragma unroll
  for (int i = 0; i < 8; ++i) o[i] = dec1_fp8(p[i]);
#endif
}

// DPP-based add from another lane (row of 16). CTRL must be an ICE.
// 0xB1 = quad_perm(1,0,3,2) -> lane^1 ; 0x4E = quad_perm(2,3,0,1) -> lane^2
// 0x128 = row_ror:8 ; 0x124 = row_ror:4
template <int CTRL>
static __device__ __forceinline__ float dpp_add_f(float x) {
  int y = __builtin_amdgcn_update_dpp(0, __float_as_int(x), CTRL, 0xf, 0xf, true);
  return x + __int_as_float(y);
}

// ---------------------------------------------------------------------------
// Fused q-projection weight: M[d][j] = sum_c qw[c][d]*W[c][j] (qW = x@M).
// Stored transposed Mt[c][j][d]; fused bias bq[c][j] = qb @ W.
// ---------------------------------------------------------------------------
__global__ void prep_fused(const float* __restrict__ qwu, const float* __restrict__ qbu,
                           const float* __restrict__ qwi, const float* __restrict__ qbi,
                           const float* __restrict__ Wui, const float* __restrict__ Wiu,
                           u16* __restrict__ Mt, float* __restrict__ bq) {
  int c = blockIdx.y, d = blockIdx.x, j = threadIdx.x;
  int l = c & 1, type = c >> 1;
  const float* qw = (type ? qwi : qwu) + l * D * D;
  const float* qb = (type ? qbi : qbu) + l * D;
  const float* W  = (type ? Wiu : Wui) + l * D * D;
  float acc = 0.f;
  for (int cc = 0; cc < D; ++cc) acc += qw[cc * D + d] * W[cc * D + j];
  Mt[((size_t)c * D + j) * D + d] = f2b(acc);
  if (d == 0) {
    float ba = 0.f;
    for (int cc = 0; cc < D; ++cc) ba += qb[cc] * W[cc * D + j];
    bq[c * D + j] = ba;
  }
}

__global__ void cast_w(const float* __restrict__ kwu, const float* __restrict__ kwi,
                       const float* __restrict__ vwu, const float* __restrict__ vwi,
                       u16* __restrict__ Wb) {
  int y = blockIdx.y;
  const float* s = (y == 0) ? kwu : (y == 1) ? kwi : (y == 2) ? vwu : vwi;
  int i = blockIdx.x * 256 + threadIdx.x;
  Wb[(size_t)y * 2 * D * D + i] = f2b(s[i]);
}

__global__ void cast_x(const float* __restrict__ x, u16* __restrict__ xb, int n2) {
  int i = blockIdx.x * 256 + threadIdx.x;
  if (i < n2) {
    float2 v = ((const float2*)x)[i];
    ((unsigned*)xb)[i] = (unsigned)f2b(v.x) | ((unsigned)f2b(v.y) << 16);
  }
}

__global__ void zero_i(int* __restrict__ p, int n) {
  int i = blockIdx.x * 256 + threadIdx.x;
  if (i < n) p[i] = 0;
}

// --------------------- CSR build via 2-level bucket sort --------------------
__global__ __launch_bounds__(256) void bhist(const int* __restrict__ dui,
                                             const int* __restrict__ diu,
                                             int* __restrict__ cnt_ui,
                                             int* __restrict__ cnt_iu, int E) {
  __shared__ int h[256];
  int t = threadIdx.x;
  h[t] = 0;
  __syncthreads();
  const int* dp = blockIdx.y ? diu : dui;
  int e0 = blockIdx.x * 1024;
#pragma unroll
  for (int i = 0; i < 4; ++i) {
    int e = e0 + i * 256 + t;
    if (e < E) atomicAdd(&h[dp[e] >> 8], 1);
  }
  __syncthreads();
  int* out = blockIdx.y ? cnt_iu : cnt_ui;
  if (h[t]) atomicAdd(&out[t], h[t]);
}

__global__ __launch_bounds__(256) void bscan(const int* __restrict__ cnt_ui,
                                             const int* __restrict__ cnt_iu,
                                             int* __restrict__ base_ui, int* __restrict__ base_iu,
                                             int* __restrict__ cur_ui, int* __restrict__ cur_iu,
                                             int* __restrict__ rp_ui, int* __restrict__ rp_iu,
                                             int nb_ui, int nb_iu, int n_ui, int n_iu, int E) {
  __shared__ int sh[256];
  int t = threadIdx.x;
  int v = (t < nb_ui) ? cnt_ui[t] : 0;
  sh[t] = v;
  __syncthreads();
  for (int off = 1; off < 256; off <<= 1) {
    int u = (t >= off) ? sh[t - off] : 0;
    __syncthreads();
    sh[t] += u;
    __syncthreads();
  }
  int ex = sh[t] - v;
  if (t < nb_ui) { base_ui[t] = ex; cur_ui[t] = ex; }
  if (t == 0) { base_ui[nb_ui] = E; rp_ui[n_ui] = E; }
  __syncthreads();
  v = (t < nb_iu) ? cnt_iu[t] : 0;
  sh[t] = v;
  __syncthreads();
  for (int off = 1; off < 256; off <<= 1) {
    int u = (t >= off) ? sh[t - off] : 0;
    __syncthreads();
    sh[t] += u;
    __syncthreads();
  }
  ex = sh[t] - v;
  if (t < nb_iu) { base_iu[t] = ex; cur_iu[t] = ex; }
  if (t == 0) { base_iu[nb_iu] = E; rp_iu[n_iu] = E; }
}

__global__ __launch_bounds__(256) void bscatter(
    const int* __restrict__ sui, const int* __restrict__ dui,
    const int* __restrict__ siu, const int* __restrict__ diu,
    int* __restrict__ cur_ui, int* __restrict__ cur_iu,
    u32* __restrict__ bb_ui, u32* __restrict__ bb_iu, int E) {
  __shared__ int h[256], rbase[256], c2[256];
  int t = threadIdx.x;
  const int* sp = blockIdx.y ? siu : sui;
  const int* dp = blockIdx.y ? diu : dui;
  int* gc = blockIdx.y ? cur_iu : cur_ui;
  u32* bb = blockIdx.y ? bb_iu : bb_ui;
  h[t] = 0;
  c2[t] = 0;
  __syncthreads();
  int e0 = blockIdx.x * 1024;
  u32 pr[4];
  int bk[4];
  bool act[4];
#pragma unroll
  for (int i = 0; i < 4; ++i) {
    int e = e0 + i * 256 + t;
    act[i] = e < E;
    if (act[i]) {
      int s = sp[e], d2 = dp[e];
      pr[i] = ((u32)d2 << 16) | (u32)s;
      bk[i] = d2 >> 8;
      atomicAdd(&h[bk[i]], 1);
    }
  }
  __syncthreads();
  if (h[t]) rbase[t] = atomicAdd(&gc[t], h[t]);
  __syncthreads();
#pragma unroll
  for (int i = 0; i < 4; ++i) {
    if (act[i]) {
      int r = atomicAdd(&c2[bk[i]], 1);
      bb[rbase[bk[i]] + r] = pr[i];
    }
  }
}

__global__ __launch_bounds__(256) void bsort(
    const u32* __restrict__ bb_ui, const u32* __restrict__ bb_iu,
    const int* __restrict__ base_ui, const int* __restrict__ base_iu,
    int* __restrict__ rp_ui, int* __restrict__ rp_iu,
    int* __restrict__ cs_ui, int* __restrict__ cs_iu,
    int nb_ui, int n_ui, int n_iu) {
  int b = blockIdx.x;
  const u32* bb; const int* base; int* rp; int* cs; int n;
  if (b < nb_ui) { bb = bb_ui; base = base_ui; rp = rp_ui; cs = cs_ui; n = n_ui; }
  else { b -= nb_ui; bb = bb_iu; base = base_iu; rp = rp_iu; cs = cs_iu; n = n_iu; }
  int lo = base[b], hi = base[b + 1];
  __shared__ int h[256], sh[256], cur[256];
  int t = threadIdx.x;
  h[t] = 0;
  __syncthreads();
  for (int j = lo + t; j < hi; j += 256) atomicAdd(&h[(bb[j] >> 16) & 255], 1);
  __syncthreads();
  int v = h[t];
  sh[t] = v;
  __syncthreads();
  for (int off = 1; off < 256; off <<= 1) {
    int u = (t >= off) ? sh[t - off] : 0;
    __syncthreads();
    sh[t] += u;
    __syncthreads();
  }
  int ex = lo + sh[t] - v;
  int gd = (b << 8) + t;
  if (gd < n) rp[gd] = ex;
  cur[t] = ex;
  __syncthreads();
  for (int j = lo + t; j < hi; j += 256) {
    u32 pr = bb[j];
    int p = atomicAdd(&cur[(pr >> 16) & 255], 1);
    cs[p] = (int)(pr & 0xffffu);
  }
}

// ---------------------------------------------------------------------------
// Merged 3-way projection for BOTH node sets. blockIdx.x < gu -> users,
// else items. blockIdx.y: 0 -> q (fp8 into Tqv lo-bytes), 1 -> k (bf16),
// 2 -> v (fp8 into Tqv hi-bytes). Tqv row (256 B):
// [q0..7 | v0..7 | q8..15 | v8..15 | ...] so dim d's q byte sits at
// (d>>3)*16 + (d&7), v at +8.
// MFMA layouts (m89/m91-verified): A[m=lane&15][k=quad*8+j];
// B[k=quad*8+j][n=lane&15]; C/D: col=lane&15, row=quad*4+reg.
// ---------------------------------------------------------------------------
__global__ __launch_bounds__(256) void gemm3(
    const u16* __restrict__ xu, const u16* __restrict__ xi,
    const u16* __restrict__ wqu, const u16* __restrict__ wku, const u16* __restrict__ wvu,
    const float* __restrict__ bqu, const float* __restrict__ bku, const float* __restrict__ bvu,
    const u16* __restrict__ wqi, const u16* __restrict__ wki, const u16* __restrict__ wvi,
    const float* __restrict__ bqi, const float* __restrict__ bki, const float* __restrict__ bvi,
    u8* __restrict__ Tqv_u, u16* __restrict__ Tk_u,
    u8* __restrict__ Tqv_i, u16* __restrict__ Tk_i,
    int gu, int nu, int ni) {
  __shared__ __align__(16) u16 wlds[128 * 136];
  int bx = blockIdx.x, y = blockIdx.y;
  bool item = bx >= gu;
  if (item) bx -= gu;
  const u16* x = item ? xi : xu;
  int nrows = item ? ni : nu;
  const u16* wt; const float* bias;
  if (y == 0)      { wt = item ? wqi : wqu; bias = item ? bqi : bqu; }
  else if (y == 1) { wt = item ? wki : wku; bias = item ? bki : bku; }
  else             { wt = item ? wvi : wvu; bias = item ? bvi : bvu; }
  u8* Tqv = item ? Tqv_i : Tqv_u;
  u16* Tk = item ? Tk_i : Tk_u;

  int t = threadIdx.x;
#pragma unroll
  for (int i = 0; i < 8; ++i) {
    int idx = t + 256 * i;
    int n = idx >> 4, kc = idx & 15;
    ((bf16x8*)wlds)[n * 17 + kc] = ((const bf16x8*)wt)[idx];
  }
  __syncthreads();
  int wave = t >> 6, lane = t & 63;
  int m = lane & 15, quad = lane >> 4;
  int row0 = bx * 64 + wave * 16;
  int arow = row0 + m;
  const bf16x8* xv = (const bf16x8*)(x + (size_t)(arow < nrows ? arow : 0) * D);
  f32x4 acc[8];
#pragma unroll
  for (int n = 0; n < 8; ++n) acc[n] = (f32x4){0.f, 0.f, 0.f, 0.f};
#pragma unroll
  for (int kk = 0; kk < 4; ++kk) {
    bf16x8 a = xv[kk * 4 + quad];
#pragma unroll
    for (int n = 0; n < 8; ++n) {
      bf16x8 b = ((const bf16x8*)wlds)[(n * 16 + m) * 17 + kk * 4 + quad];
      acc[n] = __builtin_amdgcn_mfma_f32_16x16x32_bf16(a, b, acc[n], 0, 0, 0);
    }
  }
  if (y == 1) {
#pragma unroll
    for (int n = 0; n < 8; ++n) {
      float bb = bias[n * 16 + m];
#pragma unroll
      for (int r = 0; r < 4; ++r) {
        int orow = row0 + quad * 4 + r;
        if (orow < nrows) Tk[(size_t)orow * D + n * 16 + m] = f2b(acc[n][r] + bb);
      }
    }
  } else {
    int vo = (y == 0) ? 0 : 8;
#pragma unroll
    for (int n = 0; n < 8; ++n) {
      float bb = bias[n * 16 + m];
      int dim = n * 16 + m;
      int boff = ((dim >> 3) << 4) + (dim & 7) + vo;
#pragma unroll
      for (int r = 0; r < 4; ++r) {
        int orow = row0 + quad * 4 + r;
        if (orow < nrows) Tqv[(size_t)orow * 256 + boff] = enc_fp8(acc[n][r] + bb);
      }
    }
  }
}

// ---------------------------------------------------------------------------
// Per-edge-slot work: decode q|v fp8, dot(q,k) with DPP 16-lane reduce
// (broadcast to all 16 lanes), leaky_relu+exp, accumulate p*v and z.
// ---------------------------------------------------------------------------
static __device__ __forceinline__ void do_edge(uint4 w, bool act, const float* kx,
                                               float* acc, float& z, int sub) {
  float qx[8], vx[8];
  dec8_fp8(w.x, w.y, qx);
  dec8_fp8(w.z, w.w, vx);
  float dot = 0.f;
#pragma unroll
  for (int i = 0; i < 8; ++i) dot = fmaf(qx[i], kx[i], dot);
  dot = dpp_add_f<0xB1>(dot);   // + lane^1
  dot = dpp_add_f<0x4E>(dot);   // + lane^2  -> quad-uniform
  dot = dpp_add_f<0x128>(dot);  // + quad+2 (row_ror:8)
  dot = dpp_add_f<0x124>(dot);  // + quad+1 (row_ror:4) -> full 16-lane sum
  float sc = dot * 0.08838834764831845f;  // 1/sqrt(128)
  sc = (sc > 0.f) ? sc : 0.01f * sc;      // leaky_relu
  float p = act ? __expf(sc) : 0.f;
  if (sub == 0) z += p;
#pragma unroll
  for (int i = 0; i < 8; ++i) acc[i] = fmaf(p, vx[i], acc[i]);
}

// ---------------------------------------------------------------------------
// Merged CSR aggregation for both edge types: blockIdx.x < gai -> ui
// (q/v users, k items, dst items), else iu. One wave per dst node, no agg
// atomics. q+v interleaved fp8 row (one uint4 per lane per edge), k bf16.
// Latency-pipelined: cs indices preloaded 64-wide per dst (one coalesced
// load + ds_bpermute per slot), row gathers issued 3-deep before consuming.
// ---------------------------------------------------------------------------
__global__ __launch_bounds__(256) void agg_pass(
    const u8* __restrict__ Tqv_u, const u16* __restrict__ Tk_u,
    const u8* __restrict__ Tqv_i, const u16* __restrict__ Tk_i,
    const int* __restrict__ rp_ui, const int* __restrict__ cs_ui,
    const int* __restrict__ rp_iu, const int* __restrict__ cs_iu,
    float* __restrict__ agg_u, float* __restrict__ agg_i,
    float* __restrict__ zpart, int gai, int ni, int nu) {
  int bx = blockIdx.x;
  const u8* Pqv; const u16* Pk; const int* rp; const int* cs;
  float* agg; float* zp; int ndst;
  if (bx < gai) { Pqv = Tqv_u; Pk = Tk_i; rp = rp_ui; cs = cs_ui; agg = agg_i; zp = zpart; ndst = ni; }
  else { bx -= gai; Pqv = Tqv_i; Pk = Tk_u; rp = rp_iu; cs = cs_iu; agg = agg_u; zp = zpart + 1024; ndst = nu; }
  int wave = threadIdx.x >> 6, lane = threadIdx.x & 63;
  int d = bx * 4 + wave;
  int sub = lane & 15;
  int quad = lane >> 4;
  float z = 0.f;
  float acc[8] = {0.f, 0.f, 0.f, 0.f, 0.f, 0.f, 0.f, 0.f};
  if (d < ndst) {
    bf16x8 kf = *(const bf16x8*)(Pk + (size_t)d * D + sub * 8);
    int beg = rp[d], end = rp[d + 1];
    int deg = end - beg;
    float kx[8];
#pragma unroll
    for (int i = 0; i < 8; ++i) kx[i] = b2f((u16)((short*)&kf)[i]);
    const u8* Pq = Pqv + sub * 16;
    for (int c0 = 0; c0 < deg; c0 += 64) {
      int cdeg = deg - c0;
      if (cdeg > 64) cdeg = 64;
      // one coalesced load of up to 64 edge-src indices for this dst
      int csv = (lane < cdeg) ? cs[beg + c0 + lane] : 0;
      for (int b0 = 0; b0 < cdeg; b0 += 12) {
        int i0 = b0 + quad, i1 = b0 + 4 + quad, i2 = b0 + 8 + quad;
        int s0 = __shfl(csv, i0, 64);
        int s1 = __shfl(csv, i1 < 64 ? i1 : 63, 64);
        int s2 = __shfl(csv, i2 < 64 ? i2 : 63, 64);
        // 3 independent 16B gathers in flight before first use
        uint4 w0 = *(const uint4*)(Pq + (size_t)s0 * 256);
        uint4 w1 = *(const uint4*)(Pq + (size_t)s1 * 256);
        uint4 w2 = *(const uint4*)(Pq + (size_t)s2 * 256);
        do_edge(w0, i0 < cdeg, kx, acc, z, sub);
        do_edge(w1, i1 < cdeg, kx, acc, z, sub);
        do_edge(w2, i2 < cdeg, kx, acc, z, sub);
      }
    }
#pragma unroll
    for (int i = 0; i < 8; ++i) {
      acc[i] += __shfl_xor(acc[i], 16, 64);
      acc[i] += __shfl_xor(acc[i], 32, 64);
    }
    if (quad == 0) {
      float* ap = agg + (size_t)d * D + sub * 8;
      ((f32x4*)ap)[0] = (f32x4){acc[0], acc[1], acc[2], acc[3]};
      ((f32x4*)ap)[1] = (f32x4){acc[4], acc[5], acc[6], acc[7]};
    }
    z += __shfl_xor(z, 16, 64);
    z += __shfl_xor(z, 32, 64);
  }
  __shared__ float ps[4];
  if (lane == 0) ps[wave] = z;
  __syncthreads();
  if (threadIdx.x == 0)
    unsafeAtomicAdd(&zp[blockIdx.x & 1023], ps[0] + ps[1] + ps[2] + ps[3]);
}

__global__ void zreduce(const float* __restrict__ zpart, float* __restrict__ zinv) {
  const float* zp = zpart + blockIdx.x * 1024;
  int t = threadIdx.x;
  float s = 0.f;
  for (int i = t; i < 1024; i += 256) s += zp[i];
  __shared__ float red[256];
  red[t] = s;
  __syncthreads();
  for (int k = 128; k > 0; k >>= 1) {
    if (t < k) red[t] += red[t + k];
    __syncthreads();
  }
  if (t == 0) zinv[blockIdx.x] = 1.0f / red[0];
}

__global__ void update_x(const float* __restrict__ xu, const float* __restrict__ xi,
                         const float* __restrict__ aggu, const float* __restrict__ aggi,
                         const float* __restrict__ zinv,
                         float* __restrict__ ou, float* __restrict__ oi,
                         u16* __restrict__ bu, u16* __restrict__ bi,
                         int nu, int ni, int wb) {
  int i = blockIdx.x * 256 + threadIdx.x;
  float zu = zinv[1];
  float zi = zinv[0];
  if (i < nu) {
    float v = xu[i] + aggu[i] * zu;
    ou[i] = v;
    if (wb) bu[i] = f2b(v);
  } else if (i < nu + ni) {
    int j = i - nu;
    float v = xi[j] + aggi[j] * zi;
    oi[j] = v;
    if (wb) bi[j] = f2b(v);
  }
}

extern "C" void kernel_launch(void* const* d_in, const int* in_sizes, int n_in,
                              void* d_out, int out_size, void* d_ws, size_t ws_size,
                              hipStream_t stream) {
  const float* xu_in = (const float*)d_in[0];
  const float* xi_in = (const float*)d_in[1];
  const int* ei_ui = (const int*)d_in[2];
  const int* ei_iu = (const int*)d_in[3];
  const float* qwu = (const float*)d_in[4];
  const float* qbu = (const float*)d_in[5];
  const float* kwu = (const float*)d_in[6];
  const float* kbu = (const float*)d_in[7];
  const float* vwu = (const float*)d_in[8];
  const float* vbu = (const float*)d_in[9];
  const float* qwi = (const float*)d_in[10];
  const float* qbi = (const float*)d_in[11];
  const float* kwi = (const float*)d_in[12];
  const float* kbi = (const float*)d_in[13];
  const float* vwi = (const float*)d_in[14];
  const float* vbi = (const float*)d_in[15];
  const float* Wui = (const float*)d_in[16];
  const float* Wiu = (const float*)d_in[17];

  int NU = in_sizes[0] / D;
  int NI = in_sizes[1] / D;
  int E  = in_sizes[2] / 2;

  // workspace layout (16B-aligned chunks)
  char* w = (char*)d_ws;
  float* agg_u = (float*)w;  w += (size_t)NU * D * 4;
  float* agg_i = (float*)w;  w += (size_t)NI * D * 4;
  // zero region: bcnt_ui[256], bcnt_iu[256], zpart[4096] contiguous
  int* bcnt_ui = (int*)w;    w += 256 * 4;
  int* bcnt_iu = (int*)w;    w += 256 * 4;
  float* zpart = (float*)w;  w += 4096 * 4;
  float* zinv  = (float*)w;  w += 64;
  float* bq    = (float*)w;  w += 4 * D * 4;
  int* base_ui = (int*)w;    w += 260 * 4;
  int* base_iu = (int*)w;    w += 260 * 4;
  int* cur_ui  = (int*)w;    w += 256 * 4;
  int* cur_iu  = (int*)w;    w += 256 * 4;
  int* rp_ui = (int*)w;      w += (size_t)(NI + 4) * 4;
  int* rp_iu = (int*)w;      w += (size_t)(NU + 4) * 4;
  int* cs_ui = (int*)w;      w += (size_t)E * 4;
  int* cs_iu = (int*)w;      w += (size_t)E * 4;
  u32* bb_ui = (u32*)w;      w += (size_t)E * 4;
  u32* bb_iu = (u32*)w;      w += (size_t)E * 4;
  u16* Mt  = (u16*)w;        w += (size_t)4 * D * D * 2;
  u16* Wb  = (u16*)w;        w += (size_t)8 * D * D * 2;
  u16* xub = (u16*)w;        w += (size_t)NU * D * 2;
  u16* xib = (u16*)w;        w += (size_t)NI * D * 2;
  u16* Tk_u = (u16*)w;       w += (size_t)NU * D * 2;
  u16* Tk_i = (u16*)w;       w += (size_t)NI * D * 2;
  u8* Tqv_u = (u8*)w;        w += (size_t)NU * 256;
  u8* Tqv_i = (u8*)w;

  float* out_u = (float*)d_out;
  float* out_i = out_u + (size_t)NU * D;

  prep_fused<<<dim3(128, 4), 128, 0, stream>>>(qwu, qbu, qwi, qbi, Wui, Wiu, Mt, bq);
  cast_w<<<dim3(128, 4), 256, 0, stream>>>(kwu, kwi, vwu, vwi, Wb);
  cast_x<<<(NU * D / 2 + 255) / 256, 256, 0, stream>>>(xu_in, xub, NU * D / 2);
  cast_x<<<(NI * D / 2 + 255) / 256, 256, 0, stream>>>(xi_in, xib, NI * D / 2);

  // ---- CSR build via 2-level bucket sort (edges constant across layers) ----
  int nb_ui = (NI + 255) >> 8;
  int nb_iu = (NU + 255) >> 8;
  zero_i<<<18, 256, 0, stream>>>(bcnt_ui, 512 + 4096);
  int geb = (E + 1023) / 1024;
  bhist<<<dim3(geb, 2), 256, 0, stream>>>(ei_ui + E, ei_iu + E, bcnt_ui, bcnt_iu, E);
  bscan<<<1, 256, 0, stream>>>(bcnt_ui, bcnt_iu, base_ui, base_iu, cur_ui, cur_iu,
                               rp_ui, rp_iu, nb_ui, nb_iu, NI, NU, E);
  bscatter<<<dim3(geb, 2), 256, 0, stream>>>(ei_ui, ei_ui + E, ei_iu, ei_iu + E,
                                             cur_ui, cur_iu, bb_ui, bb_iu, E);
  bsort<<<nb_ui + nb_iu, 256, 0, stream>>>(bb_ui, bb_iu, base_ui, base_iu,
                                           rp_ui, rp_iu, cs_ui, cs_iu, nb_ui, NI, NU);

  int gu = (NU + 63) / 64, gi = (NI + 63) / 64;
  int gau = (NU + 3) / 4, gai = (NI + 3) / 4;
  int gup = (NU * D + NI * D + 255) / 256;

  for (int l = 0; l < 2; ++l) {
    gemm3<<<dim3(gu + gi, 3), 256, 0, stream>>>(
        xub, xib,
        Mt + (size_t)l * D * D, Wb + (size_t)(0 + l) * D * D, Wb + (size_t)(4 + l) * D * D,
        bq + l * D, kbu + l * D, vbu + l * D,
        Mt + (size_t)(2 + l) * D * D, Wb + (size_t)(2 + l) * D * D, Wb + (size_t)(6 + l) * D * D,
        bq + (2 + l) * D, kbi + l * D, vbi + l * D,
        Tqv_u, Tk_u, Tqv_i, Tk_i, gu, NU, NI);
    agg_pass<<<gai + gau, 256, 0, stream>>>(
        Tqv_u, Tk_u, Tqv_i, Tk_i, rp_ui, cs_ui, rp_iu, cs_iu,
        agg_u, agg_i, zpart + (size_t)l * 2 * 1024, gai, NI, NU);
    zreduce<<<2, 256, 0, stream>>>(zpart + (size_t)l * 2 * 1024, zinv + l * 2);
    if (l == 0)
      update_x<<<gup, 256, 0, stream>>>(xu_in, xi_in, agg_u, agg_i, zinv + l * 2,
                                        out_u, out_i, xub, xib, NU * D, NI * D, 1);
    else
      update_x<<<gup, 256, 0, stream>>>(out_u, out_i, agg_u, agg_i, zinv + l * 2,
                                        out_u, out_i, nullptr, nullptr, NU * D, NI * D, 0);
  }
}

// Round 2
// 497.494 us; speedup vs baseline: 1.0297x; 1.0297x over previous
//
#include <hip/hip_runtime.h>
#include <stdint.h>

#define D 128

typedef __attribute__((ext_vector_type(8))) short bf16x8;
typedef __attribute__((ext_vector_type(4))) float f32x4;
typedef __attribute__((ext_vector_type(2))) float f32x2;
typedef unsigned short u16;
typedef unsigned char u8;
typedef unsigned int u32;

static __device__ __forceinline__ float b2f(u16 u) {
  return __uint_as_float(((unsigned)u) << 16);
}
static __device__ __forceinline__ u16 f2b(float f) {
  unsigned u = __float_as_uint(f);
  return (u16)((u + 0x7fffu + ((u >> 16) & 1u)) >> 16);
}

// ------------------------------ fp8 e4m3 -----------------------------------
#if defined(__has_builtin)
#if __has_builtin(__builtin_amdgcn_cvt_pk_f32_fp8) && __has_builtin(__builtin_amdgcn_cvt_pk_fp8_f32)
#define HW_FP8 1
#endif
#endif

static __device__ __forceinline__ u8 enc_fp8(float f) {
#ifdef HW_FP8
  int p = __builtin_amdgcn_cvt_pk_fp8_f32(f, 0.f, 0, false);
  return (u8)(p & 0xff);
#else
  float a = fabsf(f);
  unsigned s = (__float_as_uint(f) >> 31) << 7;
  if (a < 7.8125e-3f) {
    int m = (int)(a * 512.f + 0.5f);
    if (m > 7) m = 7;
    return (u8)(s | m);
  }
  int e; float mant = frexpf(a, &e);
  int E = e + 6;
  int m = (int)((2.f * mant - 1.f) * 8.f + 0.5f);
  if (m == 8) { m = 0; E++; }
  if (E > 15 || (E == 15 && m > 6)) { E = 15; m = 6; }
  if (E < 1) return (u8)s;
  return (u8)(s | (E << 3) | m);
#endif
}

static __device__ __forceinline__ float dec1_fp8(u8 b) {
  int e = (b >> 3) & 15, m = b & 7;
  float mag = e ? ldexpf((float)(8 + m), e - 10) : ldexpf((float)m, -9);
  return (b & 128) ? -mag : mag;
}

static __device__ __forceinline__ void dec8_fp8(u32 lo, u32 hi, float* o) {
#ifdef HW_FP8
  f32x2 a = __builtin_amdgcn_cvt_pk_f32_fp8((int)lo, false);
  f32x2 b = __builtin_amdgcn_cvt_pk_f32_fp8((int)lo, true);
  f32x2 c = __builtin_amdgcn_cvt_pk_f32_fp8((int)hi, false);
  f32x2 d = __builtin_amdgcn_cvt_pk_f32_fp8((int)hi, true);
  o[0] = a.x; o[1] = a.y; o[2] = b.x; o[3] = b.y;
  o[4] = c.x; o[5] = c.y; o[6] = d.x; o[7] = d.y;
#else
  u32 w[2] = {lo, hi};
  u8* p = (u8*)w;
#pragma unroll
  for (int i = 0; i < 8; ++i) o[i] = dec1_fp8(p[i]);
#endif
}

// DPP-based add from another lane (row of 16). CTRL must be an ICE.
// 0xB1 = quad_perm(1,0,3,2) -> lane^1 ; 0x4E = quad_perm(2,3,0,1) -> lane^2
// 0x128 = row_ror:8 ; 0x124 = row_ror:4
// (hardware-validated in R1: passed=true at absmax 0.015625)
template <int CTRL>
static __device__ __forceinline__ float dpp_add_f(float x) {
  int y = __builtin_amdgcn_update_dpp(0, __float_as_int(x), CTRL, 0xf, 0xf, true);
  return x + __int_as_float(y);
}

// ---------------------------------------------------------------------------
// Fused q-projection weight: M[d][j] = sum_c qw[c][d]*W[c][j] (qW = x@M).
// Stored transposed Mt[c][j][d]; fused bias bq[c][j] = qb @ W.
// ---------------------------------------------------------------------------
__global__ void prep_fused(const float* __restrict__ qwu, const float* __restrict__ qbu,
                           const float* __restrict__ qwi, const float* __restrict__ qbi,
                           const float* __restrict__ Wui, const float* __restrict__ Wiu,
                           u16* __restrict__ Mt, float* __restrict__ bq) {
  int c = blockIdx.y, d = blockIdx.x, j = threadIdx.x;
  int l = c & 1, type = c >> 1;
  const float* qw = (type ? qwi : qwu) + l * D * D;
  const float* qb = (type ? qbi : qbu) + l * D;
  const float* W  = (type ? Wiu : Wui) + l * D * D;
  float acc = 0.f;
  for (int cc = 0; cc < D; ++cc) acc += qw[cc * D + d] * W[cc * D + j];
  Mt[((size_t)c * D + j) * D + d] = f2b(acc);
  if (d == 0) {
    float ba = 0.f;
    for (int cc = 0; cc < D; ++cc) ba += qb[cc] * W[cc * D + j];
    bq[c * D + j] = ba;
  }
}

__global__ void cast_w(const float* __restrict__ kwu, const float* __restrict__ kwi,
                       const float* __restrict__ vwu, const float* __restrict__ vwi,
                       u16* __restrict__ Wb) {
  int y = blockIdx.y;
  const float* s = (y == 0) ? kwu : (y == 1) ? kwi : (y == 2) ? vwu : vwi;
  int i = blockIdx.x * 256 + threadIdx.x;
  Wb[(size_t)y * 2 * D * D + i] = f2b(s[i]);
}

__global__ void cast_x(const float* __restrict__ x, u16* __restrict__ xb, int n2) {
  int i = blockIdx.x * 256 + threadIdx.x;
  if (i < n2) {
    float2 v = ((const float2*)x)[i];
    ((unsigned*)xb)[i] = (unsigned)f2b(v.x) | ((unsigned)f2b(v.y) << 16);
  }
}

__global__ void zero_i(int* __restrict__ p, int n) {
  int i = blockIdx.x * 256 + threadIdx.x;
  if (i < n) p[i] = 0;
}

// --------------------- CSR build via 2-level bucket sort --------------------
__global__ __launch_bounds__(256) void bhist(const int* __restrict__ dui,
                                             const int* __restrict__ diu,
                                             int* __restrict__ cnt_ui,
                                             int* __restrict__ cnt_iu, int E) {
  __shared__ int h[256];
  int t = threadIdx.x;
  h[t] = 0;
  __syncthreads();
  const int* dp = blockIdx.y ? diu : dui;
  int e0 = blockIdx.x * 1024;
#pragma unroll
  for (int i = 0; i < 4; ++i) {
    int e = e0 + i * 256 + t;
    if (e < E) atomicAdd(&h[dp[e] >> 8], 1);
  }
  __syncthreads();
  int* out = blockIdx.y ? cnt_iu : cnt_ui;
  if (h[t]) atomicAdd(&out[t], h[t]);
}

__global__ __launch_bounds__(256) void bscan(const int* __restrict__ cnt_ui,
                                             const int* __restrict__ cnt_iu,
                                             int* __restrict__ base_ui, int* __restrict__ base_iu,
                                             int* __restrict__ cur_ui, int* __restrict__ cur_iu,
                                             int* __restrict__ rp_ui, int* __restrict__ rp_iu,
                                             int nb_ui, int nb_iu, int n_ui, int n_iu, int E) {
  __shared__ int sh[256];
  int t = threadIdx.x;
  int v = (t < nb_ui) ? cnt_ui[t] : 0;
  sh[t] = v;
  __syncthreads();
  for (int off = 1; off < 256; off <<= 1) {
    int u = (t >= off) ? sh[t - off] : 0;
    __syncthreads();
    sh[t] += u;
    __syncthreads();
  }
  int ex = sh[t] - v;
  if (t < nb_ui) { base_ui[t] = ex; cur_ui[t] = ex; }
  if (t == 0) { base_ui[nb_ui] = E; rp_ui[n_ui] = E; }
  __syncthreads();
  v = (t < nb_iu) ? cnt_iu[t] : 0;
  sh[t] = v;
  __syncthreads();
  for (int off = 1; off < 256; off <<= 1) {
    int u = (t >= off) ? sh[t - off] : 0;
    __syncthreads();
    sh[t] += u;
    __syncthreads();
  }
  ex = sh[t] - v;
  if (t < nb_iu) { base_iu[t] = ex; cur_iu[t] = ex; }
  if (t == 0) { base_iu[nb_iu] = E; rp_iu[n_iu] = E; }
}

__global__ __launch_bounds__(256) void bscatter(
    const int* __restrict__ sui, const int* __restrict__ dui,
    const int* __restrict__ siu, const int* __restrict__ diu,
    int* __restrict__ cur_ui, int* __restrict__ cur_iu,
    u32* __restrict__ bb_ui, u32* __restrict__ bb_iu, int E) {
  __shared__ int h[256], rbase[256], c2[256];
  int t = threadIdx.x;
  const int* sp = blockIdx.y ? siu : sui;
  const int* dp = blockIdx.y ? diu : dui;
  int* gc = blockIdx.y ? cur_iu : cur_ui;
  u32* bb = blockIdx.y ? bb_iu : bb_ui;
  h[t] = 0;
  c2[t] = 0;
  __syncthreads();
  int e0 = blockIdx.x * 1024;
  u32 pr[4];
  int bk[4];
  bool act[4];
#pragma unroll
  for (int i = 0; i < 4; ++i) {
    int e = e0 + i * 256 + t;
    act[i] = e < E;
    if (act[i]) {
      int s = sp[e], d2 = dp[e];
      pr[i] = ((u32)d2 << 16) | (u32)s;
      bk[i] = d2 >> 8;
      atomicAdd(&h[bk[i]], 1);
    }
  }
  __syncthreads();
  if (h[t]) rbase[t] = atomicAdd(&gc[t], h[t]);
  __syncthreads();
#pragma unroll
  for (int i = 0; i < 4; ++i) {
    if (act[i]) {
      int r = atomicAdd(&c2[bk[i]], 1);
      bb[rbase[bk[i]] + r] = pr[i];
    }
  }
}

__global__ __launch_bounds__(256) void bsort(
    const u32* __restrict__ bb_ui, const u32* __restrict__ bb_iu,
    const int* __restrict__ base_ui, const int* __restrict__ base_iu,
    int* __restrict__ rp_ui, int* __restrict__ rp_iu,
    int* __restrict__ cs_ui, int* __restrict__ cs_iu,
    int nb_ui, int n_ui, int n_iu) {
  int b = blockIdx.x;
  const u32* bb; const int* base; int* rp; int* cs; int n;
  if (b < nb_ui) { bb = bb_ui; base = base_ui; rp = rp_ui; cs = cs_ui; n = n_ui; }
  else { b -= nb_ui; bb = bb_iu; base = base_iu; rp = rp_iu; cs = cs_iu; n = n_iu; }
  int lo = base[b], hi = base[b + 1];
  __shared__ int h[256], sh[256], cur[256];
  int t = threadIdx.x;
  h[t] = 0;
  __syncthreads();
  for (int j = lo + t; j < hi; j += 256) atomicAdd(&h[(bb[j] >> 16) & 255], 1);
  __syncthreads();
  int v = h[t];
  sh[t] = v;
  __syncthreads();
  for (int off = 1; off < 256; off <<= 1) {
    int u = (t >= off) ? sh[t - off] : 0;
    __syncthreads();
    sh[t] += u;
    __syncthreads();
  }
  int ex = lo + sh[t] - v;
  int gd = (b << 8) + t;
  if (gd < n) rp[gd] = ex;
  cur[t] = ex;
  __syncthreads();
  for (int j = lo + t; j < hi; j += 256) {
    u32 pr = bb[j];
    int p = atomicAdd(&cur[(pr >> 16) & 255], 1);
    cs[p] = (int)(pr & 0xffffu);
  }
}

// ---------------------------------------------------------------------------
// Merged 3-way projection for BOTH node sets. blockIdx.x < gu -> users,
// else items. blockIdx.y: 0 -> q (fp8 into Tqv lo-bytes), 1 -> k (bf16),
// 2 -> v (fp8 into Tqv hi-bytes). Tqv row (256 B):
// [q0..7 | v0..7 | q8..15 | v8..15 | ...] so dim d's q byte sits at
// (d>>3)*16 + (d&7), v at +8.
// MFMA layouts (m89/m91-verified): A[m=lane&15][k=quad*8+j];
// B[k=quad*8+j][n=lane&15]; C/D: col=lane&15, row=quad*4+reg.
// ---------------------------------------------------------------------------
__global__ __launch_bounds__(256) void gemm3(
    const u16* __restrict__ xu, const u16* __restrict__ xi,
    const u16* __restrict__ wqu, const u16* __restrict__ wku, const u16* __restrict__ wvu,
    const float* __restrict__ bqu, const float* __restrict__ bku, const float* __restrict__ bvu,
    const u16* __restrict__ wqi, const u16* __restrict__ wki, const u16* __restrict__ wvi,
    const float* __restrict__ bqi, const float* __restrict__ bki, const float* __restrict__ bvi,
    u8* __restrict__ Tqv_u, u16* __restrict__ Tk_u,
    u8* __restrict__ Tqv_i, u16* __restrict__ Tk_i,
    int gu, int nu, int ni) {
  __shared__ __align__(16) u16 wlds[128 * 136];
  int bx = blockIdx.x, y = blockIdx.y;
  bool item = bx >= gu;
  if (item) bx -= gu;
  const u16* x = item ? xi : xu;
  int nrows = item ? ni : nu;
  const u16* wt; const float* bias;
  if (y == 0)      { wt = item ? wqi : wqu; bias = item ? bqi : bqu; }
  else if (y == 1) { wt = item ? wki : wku; bias = item ? bki : bku; }
  else             { wt = item ? wvi : wvu; bias = item ? bvi : bvu; }
  u8* Tqv = item ? Tqv_i : Tqv_u;
  u16* Tk = item ? Tk_i : Tk_u;

  int t = threadIdx.x;
#pragma unroll
  for (int i = 0; i < 8; ++i) {
    int idx = t + 256 * i;
    int n = idx >> 4, kc = idx & 15;
    ((bf16x8*)wlds)[n * 17 + kc] = ((const bf16x8*)wt)[idx];
  }
  __syncthreads();
  int wave = t >> 6, lane = t & 63;
  int m = lane & 15, quad = lane >> 4;
  int row0 = bx * 64 + wave * 16;
  int arow = row0 + m;
  const bf16x8* xv = (const bf16x8*)(x + (size_t)(arow < nrows ? arow : 0) * D);
  f32x4 acc[8];
#pragma unroll
  for (int n = 0; n < 8; ++n) acc[n] = (f32x4){0.f, 0.f, 0.f, 0.f};
#pragma unroll
  for (int kk = 0; kk < 4; ++kk) {
    bf16x8 a = xv[kk * 4 + quad];
#pragma unroll
    for (int n = 0; n < 8; ++n) {
      bf16x8 b = ((const bf16x8*)wlds)[(n * 16 + m) * 17 + kk * 4 + quad];
      acc[n] = __builtin_amdgcn_mfma_f32_16x16x32_bf16(a, b, acc[n], 0, 0, 0);
    }
  }
  if (y == 1) {
#pragma unroll
    for (int n = 0; n < 8; ++n) {
      float bb = bias[n * 16 + m];
#pragma unroll
      for (int r = 0; r < 4; ++r) {
        int orow = row0 + quad * 4 + r;
        if (orow < nrows) Tk[(size_t)orow * D + n * 16 + m] = f2b(acc[n][r] + bb);
      }
    }
  } else {
    int vo = (y == 0) ? 0 : 8;
#pragma unroll
    for (int n = 0; n < 8; ++n) {
      float bb = bias[n * 16 + m];
      int dim = n * 16 + m;
      int boff = ((dim >> 3) << 4) + (dim & 7) + vo;
#pragma unroll
      for (int r = 0; r < 4; ++r) {
        int orow = row0 + quad * 4 + r;
        if (orow < nrows) Tqv[(size_t)orow * 256 + boff] = enc_fp8(acc[n][r] + bb);
      }
    }
  }
}

// ---------------------------------------------------------------------------
// Per-edge-slot work: decode q|v fp8, dot(q,k) with DPP 16-lane reduce
// (broadcast to all 16 lanes), leaky_relu+exp, accumulate p*v and z.
// After the DPP reduce the score (and hence p) is uniform across the 16
// sub-lanes, so z is accumulated unpredicated; the later xor-16/32 quad
// reduce sums each quad exactly once per lane position.
// ---------------------------------------------------------------------------
static __device__ __forceinline__ void do_edge(uint4 w, bool act, const float* kx,
                                               float* acc, float& z) {
  float qx[8], vx[8];
  dec8_fp8(w.x, w.y, qx);
  dec8_fp8(w.z, w.w, vx);
  float dot = 0.f;
#pragma unroll
  for (int i = 0; i < 8; ++i) dot = fmaf(qx[i], kx[i], dot);
  dot = dpp_add_f<0xB1>(dot);   // + lane^1
  dot = dpp_add_f<0x4E>(dot);   // + lane^2  -> quad-of-4 uniform
  dot = dpp_add_f<0x128>(dot);  // + row_ror:8
  dot = dpp_add_f<0x124>(dot);  // + row_ror:4 -> full 16-lane sum, broadcast
  float sc = dot * 0.08838834764831845f;  // 1/sqrt(128)
  sc = (sc > 0.f) ? sc : 0.01f * sc;      // leaky_relu
  float p = act ? __expf(sc) : 0.f;
  z += p;
#pragma unroll
  for (int i = 0; i < 8; ++i) acc[i] = fmaf(p, vx[i], acc[i]);
}

// ---------------------------------------------------------------------------
// Merged CSR aggregation for both edge types: blockIdx.x < gai -> ui
// (q/v users, k items, dst items), else iu. One wave per dst node, no agg
// atomics. q+v interleaved fp8 row (one uint4 per lane per edge), k bf16.
// R0 loop structure (compiler pipelines the data-independent cs addresses),
// 2-deep edge ILP: 8 edges/iter, two independent gathers in flight.
// __launch_bounds__(256,8) pins VGPR <= 64 so occupancy stays at 8 waves/SIMD.
// ---------------------------------------------------------------------------
__global__ __launch_bounds__(256, 8) void agg_pass(
    const u8* __restrict__ Tqv_u, const u16* __restrict__ Tk_u,
    const u8* __restrict__ Tqv_i, const u16* __restrict__ Tk_i,
    const int* __restrict__ rp_ui, const int* __restrict__ cs_ui,
    const int* __restrict__ rp_iu, const int* __restrict__ cs_iu,
    float* __restrict__ agg_u, float* __restrict__ agg_i,
    float* __restrict__ zpart, int gai, int ni, int nu) {
  int bx = blockIdx.x;
  const u8* Pqv; const u16* Pk; const int* rp; const int* cs;
  float* agg; float* zp; int ndst;
  if (bx < gai) { Pqv = Tqv_u; Pk = Tk_i; rp = rp_ui; cs = cs_ui; agg = agg_i; zp = zpart; ndst = ni; }
  else { bx -= gai; Pqv = Tqv_i; Pk = Tk_u; rp = rp_iu; cs = cs_iu; agg = agg_u; zp = zpart + 1024; ndst = nu; }
  int wave = threadIdx.x >> 6, lane = threadIdx.x & 63;
  int d = bx * 4 + wave;
  int sub = lane & 15;
  int quad = lane >> 4;
  float z = 0.f;
  float acc[8] = {0.f, 0.f, 0.f, 0.f, 0.f, 0.f, 0.f, 0.f};
  if (d < ndst) {
    bf16x8 kf = *(const bf16x8*)(Pk + (size_t)d * D + sub * 8);
    int beg = rp[d], end = rp[d + 1];
    float kx[8];
#pragma unroll
    for (int i = 0; i < 8; ++i) kx[i] = b2f((u16)((short*)&kf)[i]);
    const u8* Pq = Pqv + sub * 16;
    int iters = (end - beg + 7) >> 3;
    for (int it = 0; it < iters; ++it) {
      int j0 = beg + it * 8 + quad;
      int j1 = j0 + 4;
      bool a0 = j0 < end, a1 = j1 < end;
      int s0 = a0 ? cs[j0] : 0;
      int s1 = a1 ? cs[j1] : 0;
      // two independent 16B gathers in flight before first use
      uint4 w0 = *(const uint4*)(Pq + (size_t)s0 * 256);
      uint4 w1 = *(const uint4*)(Pq + (size_t)s1 * 256);
      do_edge(w0, a0, kx, acc, z);
      do_edge(w1, a1, kx, acc, z);
    }
#pragma unroll
    for (int i = 0; i < 8; ++i) {
      acc[i] += __shfl_xor(acc[i], 16, 64);
      acc[i] += __shfl_xor(acc[i], 32, 64);
    }
    if (quad == 0) {
      float* ap = agg + (size_t)d * D + sub * 8;
      ((f32x4*)ap)[0] = (f32x4){acc[0], acc[1], acc[2], acc[3]};
      ((f32x4*)ap)[1] = (f32x4){acc[4], acc[5], acc[6], acc[7]};
    }
    z += __shfl_xor(z, 16, 64);
    z += __shfl_xor(z, 32, 64);
  }
  __shared__ float ps[4];
  if (lane == 0) ps[wave] = z;
  __syncthreads();
  if (threadIdx.x == 0)
    unsafeAtomicAdd(&zp[blockIdx.x & 1023], ps[0] + ps[1] + ps[2] + ps[3]);
}

__global__ void zreduce(const float* __restrict__ zpart, float* __restrict__ zinv) {
  const float* zp = zpart + blockIdx.x * 1024;
  int t = threadIdx.x;
  float s = 0.f;
  for (int i = t; i < 1024; i += 256) s += zp[i];
  __shared__ float red[256];
  red[t] = s;
  __syncthreads();
  for (int k = 128; k > 0; k >>= 1) {
    if (t < k) red[t] += red[t + k];
    __syncthreads();
  }
  if (t == 0) zinv[blockIdx.x] = 1.0f / red[0];
}

__global__ void update_x(const float* __restrict__ xu, const float* __restrict__ xi,
                         const float* __restrict__ aggu, const float* __restrict__ aggi,
                         const float* __restrict__ zinv,
                         float* __restrict__ ou, float* __restrict__ oi,
                         u16* __restrict__ bu, u16* __restrict__ bi,
                         int nu, int ni, int wb) {
  int i = blockIdx.x * 256 + threadIdx.x;
  float zu = zinv[1];
  float zi = zinv[0];
  if (i < nu) {
    float v = xu[i] + aggu[i] * zu;
    ou[i] = v;
    if (wb) bu[i] = f2b(v);
  } else if (i < nu + ni) {
    int j = i - nu;
    float v = xi[j] + aggi[j] * zi;
    oi[j] = v;
    if (wb) bi[j] = f2b(v);
  }
}

extern "C" void kernel_launch(void* const* d_in, const int* in_sizes, int n_in,
                              void* d_out, int out_size, void* d_ws, size_t ws_size,
                              hipStream_t stream) {
  const float* xu_in = (const float*)d_in[0];
  const float* xi_in = (const float*)d_in[1];
  const int* ei_ui = (const int*)d_in[2];
  const int* ei_iu = (const int*)d_in[3];
  const float* qwu = (const float*)d_in[4];
  const float* qbu = (const float*)d_in[5];
  const float* kwu = (const float*)d_in[6];
  const float* kbu = (const float*)d_in[7];
  const float* vwu = (const float*)d_in[8];
  const float* vbu = (const float*)d_in[9];
  const float* qwi = (const float*)d_in[10];
  const float* qbi = (const float*)d_in[11];
  const float* kwi = (const float*)d_in[12];
  const float* kbi = (const float*)d_in[13];
  const float* vwi = (const float*)d_in[14];
  const float* vbi = (const float*)d_in[15];
  const float* Wui = (const float*)d_in[16];
  const float* Wiu = (const float*)d_in[17];

  int NU = in_sizes[0] / D;
  int NI = in_sizes[1] / D;
  int E  = in_sizes[2] / 2;

  // workspace layout (16B-aligned chunks)
  char* w = (char*)d_ws;
  float* agg_u = (float*)w;  w += (size_t)NU * D * 4;
  float* agg_i = (float*)w;  w += (size_t)NI * D * 4;
  // zero region: bcnt_ui[256], bcnt_iu[256], zpart[4096] contiguous
  int* bcnt_ui = (int*)w;    w += 256 * 4;
  int* bcnt_iu = (int*)w;    w += 256 * 4;
  float* zpart = (float*)w;  w += 4096 * 4;
  float* zinv  = (float*)w;  w += 64;
  float* bq    = (float*)w;  w += 4 * D * 4;
  int* base_ui = (int*)w;    w += 260 * 4;
  int* base_iu = (int*)w;    w += 260 * 4;
  int* cur_ui  = (int*)w;    w += 256 * 4;
  int* cur_iu  = (int*)w;    w += 256 * 4;
  int* rp_ui = (int*)w;      w += (size_t)(NI + 4) * 4;
  int* rp_iu = (int*)w;      w += (size_t)(NU + 4) * 4;
  int* cs_ui = (int*)w;      w += (size_t)E * 4;
  int* cs_iu = (int*)w;      w += (size_t)E * 4;
  u32* bb_ui = (u32*)w;      w += (size_t)E * 4;
  u32* bb_iu = (u32*)w;      w += (size_t)E * 4;
  u16* Mt  = (u16*)w;        w += (size_t)4 * D * D * 2;
  u16* Wb  = (u16*)w;        w += (size_t)8 * D * D * 2;
  u16* xub = (u16*)w;        w += (size_t)NU * D * 2;
  u16* xib = (u16*)w;        w += (size_t)NI * D * 2;
  u16* Tk_u = (u16*)w;       w += (size_t)NU * D * 2;
  u16* Tk_i = (u16*)w;       w += (size_t)NI * D * 2;
  u8* Tqv_u = (u8*)w;        w += (size_t)NU * 256;
  u8* Tqv_i = (u8*)w;

  float* out_u = (float*)d_out;
  float* out_i = out_u + (size_t)NU * D;

  prep_fused<<<dim3(128, 4), 128, 0, stream>>>(qwu, qbu, qwi, qbi, Wui, Wiu, Mt, bq);
  cast_w<<<dim3(128, 4), 256, 0, stream>>>(kwu, kwi, vwu, vwi, Wb);
  cast_x<<<(NU * D / 2 + 255) / 256, 256, 0, stream>>>(xu_in, xub, NU * D / 2);
  cast_x<<<(NI * D / 2 + 255) / 256, 256, 0, stream>>>(xi_in, xib, NI * D / 2);

  // ---- CSR build via 2-level bucket sort (edges constant across layers) ----
  int nb_ui = (NI + 255) >> 8;
  int nb_iu = (NU + 255) >> 8;
  zero_i<<<18, 256, 0, stream>>>(bcnt_ui, 512 + 4096);
  int geb = (E + 1023) / 1024;
  bhist<<<dim3(geb, 2), 256, 0, stream>>>(ei_ui + E, ei_iu + E, bcnt_ui, bcnt_iu, E);
  bscan<<<1, 256, 0, stream>>>(bcnt_ui, bcnt_iu, base_ui, base_iu, cur_ui, cur_iu,
                               rp_ui, rp_iu, nb_ui, nb_iu, NI, NU, E);
  bscatter<<<dim3(geb, 2), 256, 0, stream>>>(ei_ui, ei_ui + E, ei_iu, ei_iu + E,
                                             cur_ui, cur_iu, bb_ui, bb_iu, E);
  bsort<<<nb_ui + nb_iu, 256, 0, stream>>>(bb_ui, bb_iu, base_ui, base_iu,
                                           rp_ui, rp_iu, cs_ui, cs_iu, nb_ui, NI, NU);

  int gu = (NU + 63) / 64, gi = (NI + 63) / 64;
  int gau = (NU + 3) / 4, gai = (NI + 3) / 4;
  int gup = (NU * D + NI * D + 255) / 256;

  for (int l = 0; l < 2; ++l) {
    gemm3<<<dim3(gu + gi, 3), 256, 0, stream>>>(
        xub, xib,
        Mt + (size_t)l * D * D, Wb + (size_t)(0 + l) * D * D, Wb + (size_t)(4 + l) * D * D,
        bq + l * D, kbu + l * D, vbu + l * D,
        Mt + (size_t)(2 + l) * D * D, Wb + (size_t)(2 + l) * D * D, Wb + (size_t)(6 + l) * D * D,
        bq + (2 + l) * D, kbi + l * D, vbi + l * D,
        Tqv_u, Tk_u, Tqv_i, Tk_i, gu, NU, NI);
    agg_pass<<<gai + gau, 256, 0, stream>>>(
        Tqv_u, Tk_u, Tqv_i, Tk_i, rp_ui, cs_ui, rp_iu, cs_iu,
        agg_u, agg_i, zpart + (size_t)l * 2 * 1024, gai, NI, NU);
    zreduce<<<2, 256, 0, stream>>>(zpart + (size_t)l * 2 * 1024, zinv + l * 2);
    if (l == 0)
      update_x<<<gup, 256, 0, stream>>>(xu_in, xi_in, agg_u, agg_i, zinv + l * 2,
                                        out_u, out_i, xub, xib, NU * D, NI * D, 1);
    else
      update_x<<<gup, 256, 0, stream>>>(out_u, out_i, agg_u, agg_i, zinv + l * 2,
                                        out_u, out_i, nullptr, nullptr, NU * D, NI * D, 0);
  }
}